// Round 1
// baseline (95.186 us; speedup 1.0000x reference)
//
#include <hip/hip_runtime.h>
#include <cmath>

#define PHI_F 1.6180339887498949f

// ---------------------------------------------------------------------------
// Phase 1: elementwise rotation recurrence over S=64 steps.
// carry (h_real, h_imag) per (b, d); only the final step's h = h_r + h_i
// feeds the layer stack. One block per batch row, one thread per d.
// ---------------------------------------------------------------------------
__global__ __launch_bounds__(512) void rin_recurrence(
    const int* __restrict__ ids,      // (128, 64)
    const float* __restrict__ te,     // (1024, 1024): [0:512]=w, [512:1024]=b
    float* __restrict__ h)            // out: (128, 512)
{
    const int b = blockIdx.x;   // 0..127
    const int d = threadIdx.x;  // 0..511
    float hr = 0.f, hi = 0.f;
    #pragma unroll 1
    for (int t = 0; t < 64; ++t) {
        const int id = ids[b * 64 + t];
        const float w  = te[id * 1024 + d];
        const float be = te[id * 1024 + 512 + d];
        const float tv = (float)t * PHI_F;
        const float lam = 1.0f + fabsf(w);
        const float thr = hr / lam + be + tv;
        const float thi = hi / lam + be + tv;
        float sr, cr, si, ci;
        sincosf(thr, &sr, &cr);
        sincosf(thi, &si, &ci);
        hr = cr * ci - sr * si;   // cos(thr + thi)
        hi = cr * si + sr * ci;   // sin(thr + thi)
    }
    h[b * 512 + d] = hr + hi;
}

// ---------------------------------------------------------------------------
// Split-K NT GEMM: C[m][n] = sum_k A[m][k] * B[n][k], partials per k-split.
// BM=BN=64, BK=32, 256 threads, 4x4 register tile.
// DUAL: K axis is the concat of (A,B) and (A2,B2), each of length K.
// part layout: part[(sp*M + m)*N + n]
// ---------------------------------------------------------------------------
template<bool DUAL>
__global__ __launch_bounds__(256) void gemm_nt_partial(
    const float* __restrict__ A,  const float* __restrict__ A2,
    const float* __restrict__ B,  const float* __restrict__ B2,
    int M, int N, int K, int Ktot, int splits,
    float* __restrict__ part)
{
    constexpr int BM = 64, BN = 64, BK = 32;
    __shared__ float As[BK][BM + 4];
    __shared__ float Bs[BK][BN + 4];
    const int tid = threadIdx.x;
    const int nT = blockIdx.x, mT = blockIdx.y, sp = blockIdx.z;
    const int m0 = mT * BM, n0 = nT * BN;
    const int kchunk = Ktot / splits;
    const int kbeg = sp * kchunk;
    const int lrow = tid >> 3;          // 0..31
    const int lcol = (tid & 7) << 2;    // 0,4,...,28
    const int ty = tid >> 4;            // 0..15 -> m
    const int tx = tid & 15;            // 0..15 -> n
    float acc[4][4] = {{0.f}};

    for (int kt = 0; kt < kchunk; kt += BK) {
        const int kg = kbeg + kt;
        const float* Ap; const float* Bp; int kk;
        if (!DUAL || kg < K) { Ap = A;  Bp = B;  kk = kg; }
        else                 { Ap = A2; Bp = B2; kk = kg - K; }

        const float4 a0 = *(const float4*)(Ap + (size_t)(m0 + lrow)      * K + kk + lcol);
        const float4 a1 = *(const float4*)(Ap + (size_t)(m0 + lrow + 32) * K + kk + lcol);
        const float4 b0 = *(const float4*)(Bp + (size_t)(n0 + lrow)      * K + kk + lcol);
        const float4 b1 = *(const float4*)(Bp + (size_t)(n0 + lrow + 32) * K + kk + lcol);

        __syncthreads();
        As[lcol + 0][lrow] = a0.x; As[lcol + 1][lrow] = a0.y;
        As[lcol + 2][lrow] = a0.z; As[lcol + 3][lrow] = a0.w;
        As[lcol + 0][lrow + 32] = a1.x; As[lcol + 1][lrow + 32] = a1.y;
        As[lcol + 2][lrow + 32] = a1.z; As[lcol + 3][lrow + 32] = a1.w;
        Bs[lcol + 0][lrow] = b0.x; Bs[lcol + 1][lrow] = b0.y;
        Bs[lcol + 2][lrow] = b0.z; Bs[lcol + 3][lrow] = b0.w;
        Bs[lcol + 0][lrow + 32] = b1.x; Bs[lcol + 1][lrow + 32] = b1.y;
        Bs[lcol + 2][lrow + 32] = b1.z; Bs[lcol + 3][lrow + 32] = b1.w;
        __syncthreads();

        #pragma unroll
        for (int k2 = 0; k2 < BK; ++k2) {
            const float4 av = *(const float4*)&As[k2][ty * 4];
            const float4 bv = *(const float4*)&Bs[k2][tx * 4];
            acc[0][0] += av.x * bv.x; acc[0][1] += av.x * bv.y;
            acc[0][2] += av.x * bv.z; acc[0][3] += av.x * bv.w;
            acc[1][0] += av.y * bv.x; acc[1][1] += av.y * bv.y;
            acc[1][2] += av.y * bv.z; acc[1][3] += av.y * bv.w;
            acc[2][0] += av.z * bv.x; acc[2][1] += av.z * bv.y;
            acc[2][2] += av.z * bv.z; acc[2][3] += av.z * bv.w;
            acc[3][0] += av.w * bv.x; acc[3][1] += av.w * bv.y;
            acc[3][2] += av.w * bv.z; acc[3][3] += av.w * bv.w;
        }
    }

    float* pbase = part + ((size_t)sp * M + m0 + ty * 4) * N + n0 + tx * 4;
    #pragma unroll
    for (int i = 0; i < 4; ++i) {
        float4 v;
        v.x = acc[i][0]; v.y = acc[i][1]; v.z = acc[i][2]; v.w = acc[i][3];
        *(float4*)(pbase + (size_t)i * N) = v;
    }
}

// ---------------------------------------------------------------------------
// Reduce epilogues
// ---------------------------------------------------------------------------
// theta = sum(partials) + bias[n] + t_last; ct=cos(theta), st=sin(theta)
__global__ __launch_bounds__(256) void reduce_trig(
    const float* __restrict__ part, const float* __restrict__ bias,
    float tlast, float* __restrict__ ct, float* __restrict__ st)
{
    const int idx = blockIdx.x * 256 + threadIdx.x;  // < 131072 (128x1024)
    float s = 0.f;
    #pragma unroll
    for (int sp = 0; sp < 8; ++sp) s += part[(size_t)sp * 131072 + idx];
    const float theta = s + bias[idx & 1023] + tlast;
    float sn, cs;
    sincosf(theta, &sn, &cs);
    ct[idx] = cs;
    st[idx] = sn;
}

// h += silu(sum(partials))
__global__ __launch_bounds__(256) void reduce_silu(
    const float* __restrict__ part, float* __restrict__ h)
{
    const int idx = blockIdx.x * 256 + threadIdx.x;  // < 65536 (128x512)
    float s = 0.f;
    #pragma unroll
    for (int sp = 0; sp < 16; ++sp) s += part[(size_t)sp * 65536 + idx];
    h[idx] += s / (1.0f + expf(-s));   // x * sigmoid(x)
}

// out = sum(partials)
__global__ __launch_bounds__(256) void reduce_out(
    const float* __restrict__ part, float* __restrict__ out)
{
    const int idx = blockIdx.x * 256 + threadIdx.x;  // < 131072 (128x1024)
    float s = 0.f;
    #pragma unroll
    for (int sp = 0; sp < 8; ++sp) s += part[(size_t)sp * 131072 + idx];
    out[idx] = s;
}

// ---------------------------------------------------------------------------
// B=128, S=64, V=1024, D=512, N=1024, L=2
// inputs: 0 ids(128,64) i32 | 1 te(1024,1024) | 2 W(2,1024,512) | 3 bias(2,1024)
//         4 Pr(2,512,1024) | 5 Pi(2,512,1024) | 6 oproj(1024,512)
// out: (128,1024) f32
// ws: h 64K | ct 128K | st 128K | part 1M floats  (~5.3 MB)
// ---------------------------------------------------------------------------
extern "C" void kernel_launch(void* const* d_in, const int* in_sizes, int n_in,
                              void* d_out, int out_size, void* d_ws, size_t ws_size,
                              hipStream_t stream) {
    const int*   ids   = (const int*)d_in[0];
    const float* te    = (const float*)d_in[1];
    const float* W     = (const float*)d_in[2];
    const float* bias  = (const float*)d_in[3];
    const float* Pr    = (const float*)d_in[4];
    const float* Pi    = (const float*)d_in[5];
    const float* oproj = (const float*)d_in[6];
    float* out = (float*)d_out;

    float* ws   = (float*)d_ws;
    float* h    = ws;                 // 65536
    float* ct   = h + 65536;          // 131072
    float* st   = ct + 131072;        // 131072
    float* part = st + 131072;        // 1048576

    rin_recurrence<<<128, 512, 0, stream>>>(ids, te, h);

    const float TLAST = 63.0f * PHI_F;
    for (int l = 0; l < 2; ++l) {
        // theta = h @ W_l^T  (M=128, N=1024, K=512), split-K 8 -> 256 blocks
        gemm_nt_partial<false><<<dim3(16, 2, 8), 256, 0, stream>>>(
            h, nullptr, W + (size_t)l * 1024 * 512, nullptr,
            128, 1024, 512, 512, 8, part);
        reduce_trig<<<512, 256, 0, stream>>>(part, bias + l * 1024, TLAST, ct, st);

        // out = ct @ Pr_l^T + st @ Pi_l^T  (M=128, N=512, Ktot=2048), split-K 16
        gemm_nt_partial<true><<<dim3(8, 2, 16), 256, 0, stream>>>(
            ct, st, Pr + (size_t)l * 512 * 1024, Pi + (size_t)l * 512 * 1024,
            128, 512, 1024, 2048, 16, part);
        reduce_silu<<<256, 256, 0, stream>>>(part, h);
    }

    // logits = h @ oproj^T  (M=128, N=1024, K=512), split-K 8
    gemm_nt_partial<false><<<dim3(16, 2, 8), 256, 0, stream>>>(
        h, nullptr, oproj, nullptr, 128, 1024, 512, 512, 8, part);
    reduce_out<<<512, 256, 0, stream>>>(part, out);
}